// Round 1
// baseline (621.199 us; speedup 1.0000x reference)
//
#include <hip/hip_runtime.h>
#include <hip/hip_fp16.h>
#include <math.h>

// GILR model: T=2048 B=32 IN=256 H=512 F=2048 OUT=256
// Pipeline:
//   prep: f32->f16 convert of x, Wg|Wi (stacked), W1, W2; concat bg|bi
//   GEMM1: pre[m,0:512]=x@Wg^T+bg, pre[m,512:1024]=x@Wi^T+bi  (f16 out, 65536x1024)
//   scan : 3-pass chunked associative scan over T; writes h (f16) in-place over pre-g slots
//   4 T-slabs of 512: GEMM2: z=gelu(h@W1^T+b1) f16 ; GEMM3: out=z@W2^T+b2 f32
// All GEMMs: f16 MFMA 16x16x32, fp32 accum, 128x128 tile, 4 waves, BK=64,
// double-buffered LDS via global_load_lds width-16 (m97 structure, un-swizzled).

#define T_DIM 2048
#define B_DIM 32
#define IN_DIM 256
#define H_DIM 512
#define F_DIM 2048
#define OUT_DIM 256
#define M_TOTAL (T_DIM * B_DIM)   // 65536

typedef _Float16 f16;
typedef _Float16 f16x8 __attribute__((ext_vector_type(8)));
typedef float f32x4 __attribute__((ext_vector_type(4)));

#define AS3(p) ((__attribute__((address_space(3))) void*)(p))
#define AS1(p) ((const __attribute__((address_space(1))) void*)(p))

// ---------------- conversion kernels ----------------

__global__ void cvt_kernel(const float* __restrict__ in, f16* __restrict__ out, int n8) {
  int i = blockIdx.x * blockDim.x + threadIdx.x;
  if (i >= n8) return;
  const float4* p = (const float4*)in + (size_t)i * 2;
  float4 a = p[0], b = p[1];
  f16x8 o = { (f16)a.x, (f16)a.y, (f16)a.z, (f16)a.w,
              (f16)b.x, (f16)b.y, (f16)b.z, (f16)b.w };
  *((f16x8*)out + i) = o;
}

__global__ void bias_cat_kernel(const float* __restrict__ bg, const float* __restrict__ bi,
                                float* __restrict__ bgi) {
  int t = threadIdx.x;  // 1024 threads
  bgi[t] = (t < 512) ? bg[t] : bi[t - 512];
}

// ---------------- generic BT GEMM ----------------
// C[m,n] = act( sum_k A[m,k]*Bw[n,k] + bias[n] )
// MODE 0: store f16 (no act) ; MODE 1: exact-gelu, store f16 ; MODE 2: store f32 (no act)

template <int MODE>
__global__ __launch_bounds__(256, 2) void gemm_bt(
    const f16* __restrict__ A, const f16* __restrict__ Bw,
    const float* __restrict__ bias, void* __restrict__ Cout,
    int lda, int ldb, int ldc, int K) {
  __shared__ f16 lds[2][2][128][64];   // [dbuf][A/B][row][k] = 64 KiB
  const int tid = threadIdx.x;
  const int wid = tid >> 6, lane = tid & 63;
  const int m0 = blockIdx.x * 128, n0 = blockIdx.y * 128;
  const int wr = (wid >> 1) * 64;  // wave row offset in tile
  const int wc = (wid & 1) * 64;   // wave col offset in tile
  const int NT = K >> 6;

  auto stage = [&](int buf, int kt) {
    const f16* ga = A + (size_t)m0 * lda + kt * 64;
    const f16* gb = Bw + (size_t)n0 * ldb + kt * 64;
    f16* la = &lds[buf][0][0][0];
    f16* lb = &lds[buf][1][0][0];
#pragma unroll
    for (int q = 0; q < 4; ++q) {
      int seg = (wid << 2) + q;          // 0..15, wave-uniform
      int s = seg * 64 + lane;           // 16B slot index 0..1023
      int row = s >> 3, col = (s & 7) << 3;
      __builtin_amdgcn_global_load_lds(AS1(ga + (size_t)row * lda + col),
                                       AS3(la + seg * 512), 16, 0, 0);
      __builtin_amdgcn_global_load_lds(AS1(gb + (size_t)row * ldb + col),
                                       AS3(lb + seg * 512), 16, 0, 0);
    }
  };

  f32x4 acc[4][4] = {};
  stage(0, 0);
  for (int kt = 0; kt < NT; ++kt) {
    __syncthreads();  // staged buf[kt&1] visible; all waves done with buf[(kt+1)&1]
    if (kt + 1 < NT) stage((kt + 1) & 1, kt + 1);
    f16(*At)[64] = lds[kt & 1][0];
    f16(*Bt)[64] = lds[kt & 1][1];
    const int r = lane & 15, cg = (lane >> 4) << 3;
#pragma unroll
    for (int kk = 0; kk < 2; ++kk) {
      f16x8 af[4], bf[4];
#pragma unroll
      for (int i = 0; i < 4; ++i)
        af[i] = *(const f16x8*)&At[wr + i * 16 + r][kk * 32 + cg];
#pragma unroll
      for (int i = 0; i < 4; ++i)
        bf[i] = *(const f16x8*)&Bt[wc + i * 16 + r][kk * 32 + cg];
#pragma unroll
      for (int mi = 0; mi < 4; ++mi)
#pragma unroll
        for (int ni = 0; ni < 4; ++ni)
          acc[mi][ni] = __builtin_amdgcn_mfma_f32_16x16x32_f16(af[mi], bf[ni], acc[mi][ni], 0, 0, 0);
    }
  }

  // epilogue: C/D layout col=lane&15, row=(lane>>4)*4+j (m89-verified, dtype-indep)
  const int r = lane & 15, rq = (lane >> 4) * 4;
#pragma unroll
  for (int ni = 0; ni < 4; ++ni) {
    int col = n0 + wc + ni * 16 + r;
    float bv = bias[col];
#pragma unroll
    for (int mi = 0; mi < 4; ++mi) {
#pragma unroll
      for (int j = 0; j < 4; ++j) {
        int row = m0 + wr + mi * 16 + rq + j;
        float v = acc[mi][ni][j] + bv;
        if constexpr (MODE == 1) v = 0.5f * v * (1.0f + erff(v * 0.70710678118f));
        if constexpr (MODE == 2)
          ((float*)Cout)[(size_t)row * ldc + col] = v;
        else
          ((f16*)Cout)[(size_t)row * ldc + col] = (f16)v;
      }
    }
  }
}

// ---------------- scan (3-pass chunked) ----------------
// ab layout: row m = t*32+b, 1024 cols: [0:512)=pre_g, [512:1024)=pre_i (f16)
// channel ch = b*512+h ; addr(t,ch) = t*32768 + (ch>>9)*1024 + (ch&511)
// h_t = g_t*h_{t-1} + (1-g_t)*i_t

#define NCH 16384
#define NCHUNK 32
#define CLEN 64

__global__ void scan_p1(const f16* __restrict__ ab, float* __restrict__ cA,
                        float* __restrict__ cH) {
  int ch = blockIdx.x * 256 + threadIdx.x;
  int c = blockIdx.y;
  const f16* pg = ab + (size_t)(c * CLEN) * 32768 + (ch >> 9) * 1024 + (ch & 511);
  const f16* pi = pg + 512;
  float A = 1.f, Hl = 0.f;
  for (int t = 0; t < CLEN; ++t) {
    float g = 1.f / (1.f + expf(-(float)pg[0]));
    float ii = tanhf((float)pi[0]);
    Hl = g * Hl + (1.f - g) * ii;
    A *= g;
    pg += 32768; pi += 32768;
  }
  cA[c * NCH + ch] = A;
  cH[c * NCH + ch] = Hl;
}

__global__ void scan_p2(const float* __restrict__ cA, const float* __restrict__ cH,
                        float* __restrict__ st) {
  int ch = blockIdx.x * 256 + threadIdx.x;
  float h0 = 0.f;
  for (int c = 0; c < NCHUNK; ++c) {
    st[c * NCH + ch] = h0;
    h0 = cA[c * NCH + ch] * h0 + cH[c * NCH + ch];
  }
}

__global__ void scan_p3(f16* __restrict__ ab, const float* __restrict__ st) {
  int ch = blockIdx.x * 256 + threadIdx.x;
  int c = blockIdx.y;
  f16* pg = ab + (size_t)(c * CLEN) * 32768 + (ch >> 9) * 1024 + (ch & 511);
  const f16* pi = pg + 512;
  float hv = st[c * NCH + ch];
  for (int t = 0; t < CLEN; ++t) {
    float g = 1.f / (1.f + expf(-(float)pg[0]));
    float ii = tanhf((float)pi[0]);
    hv = g * hv + (1.f - g) * ii;
    pg[0] = (f16)hv;   // in-place: h over pre_g slot (after read)
    pg += 32768; pi += 32768;
  }
}

// ---------------- launch ----------------

extern "C" void kernel_launch(void* const* d_in, const int* in_sizes, int n_in,
                              void* d_out, int out_size, void* d_ws, size_t ws_size,
                              hipStream_t stream) {
  const float* x  = (const float*)d_in[0];
  const float* Wg = (const float*)d_in[1];
  const float* bg = (const float*)d_in[2];
  const float* Wi = (const float*)d_in[3];
  const float* bi = (const float*)d_in[4];
  const float* W1 = (const float*)d_in[5];
  const float* b1 = (const float*)d_in[6];
  const float* W2 = (const float*)d_in[7];
  const float* b2 = (const float*)d_in[8];
  float* out = (float*)d_out;

  char* ws = (char*)d_ws;
  // workspace layout (bytes)
  f16*   wgi16 = (f16*)(ws + 0);            // 1024x256 f16      = 524288
  f16*   w116  = (f16*)(ws + 524288);       // 2048x512 f16      = 2097152
  f16*   w216  = (f16*)(ws + 2621440);      // 256x2048 f16      = 1048576
  float* bgi   = (float*)(ws + 3670016);    // 1024 f32
  f16*   x16   = (f16*)(ws + 4194304);      // 65536x256 f16     = 33554432
  f16*   ab16  = (f16*)(ws + 37748736);     // 65536x1024 f16    = 134217728
  float* cA    = (float*)(ws + 171966464);  // 32x16384 f32      = 2097152
  float* cH    = (float*)(ws + 174063616);  // 32x16384 f32      = 2097152
  float* st    = (float*)(ws + 176160768);  // 32x16384 f32      = 2097152
  f16*   z16   = (f16*)(ws + 178257920);    // 16384x2048 f16    = 67108864
  if (ws_size < 245366784) return;          // need ~234 MiB

  // prep
  cvt_kernel<<<64, 256, 0, stream>>>(Wg, wgi16, 16384);
  cvt_kernel<<<64, 256, 0, stream>>>(Wi, wgi16 + 131072, 16384);
  cvt_kernel<<<512, 256, 0, stream>>>(W1, w116, 131072);
  cvt_kernel<<<256, 256, 0, stream>>>(W2, w216, 65536);
  bias_cat_kernel<<<1, 1024, 0, stream>>>(bg, bi, bgi);
  cvt_kernel<<<8192, 256, 0, stream>>>(x, x16, 2097152);

  // GEMM1: pre = x @ [Wg;Wi]^T + [bg;bi]  -> ab16 (f16, ldc=1024)
  gemm_bt<0><<<dim3(512, 8), 256, 0, stream>>>(x16, wgi16, bgi, ab16,
                                               IN_DIM, IN_DIM, 1024, IN_DIM);

  // scan
  scan_p1<<<dim3(64, NCHUNK), 256, 0, stream>>>(ab16, cA, cH);
  scan_p2<<<64, 256, 0, stream>>>(cA, cH, st);
  scan_p3<<<dim3(64, NCHUNK), 256, 0, stream>>>(ab16, st);

  // 4 T-slabs: GEMM2 (gelu) -> z16 ; GEMM3 -> out
  for (int s = 0; s < 4; ++s) {
    const f16* hs = ab16 + (size_t)s * 16384 * 1024;
    gemm_bt<1><<<dim3(128, 16), 256, 0, stream>>>(hs, w116, b1, z16,
                                                  1024, H_DIM, F_DIM, H_DIM);
    gemm_bt<2><<<dim3(128, 2), 256, 0, stream>>>(z16, w216, b2,
                                                 out + (size_t)s * 16384 * 256,
                                                 F_DIM, F_DIM, OUT_DIM, F_DIM);
  }
}

// Round 2
// 587.550 us; speedup vs baseline: 1.0573x; 1.0573x over previous
//
#include <hip/hip_runtime.h>
#include <hip/hip_fp16.h>
#include <math.h>

// GILR model: T=2048 B=32 IN=256 H=512 F=2048 OUT=256
//   prep: f32->f16 convert of x, Wg|Wi (stacked), W1, W2; concat bg|bi
//   GEMM1: pre = x@[Wg;Wi]^T + [bg;bi]  (f16, 65536x1024)  [m97 128-tile structure]
//   scan : 3-pass chunked associative scan; h written in-place over pre_g
//   4 T-slabs: GEMM2 (8-phase 256^2 template, fast-gelu, f16) ; GEMM3 (m97 structure, f32)

#define T_DIM 2048
#define B_DIM 32
#define IN_DIM 256
#define H_DIM 512
#define F_DIM 2048
#define OUT_DIM 256

typedef _Float16 f16;
typedef _Float16 f16x8 __attribute__((ext_vector_type(8)));
typedef float f32x4 __attribute__((ext_vector_type(4)));

#define AS3(p) ((__attribute__((address_space(3))) void*)(p))
#define AS1(p) ((const __attribute__((address_space(1))) void*)(p))

// ---------------- conversion kernels ----------------

__global__ void cvt_kernel(const float* __restrict__ in, f16* __restrict__ out, int n8) {
  int i = blockIdx.x * blockDim.x + threadIdx.x;
  if (i >= n8) return;
  const float4* p = (const float4*)in + (size_t)i * 2;
  float4 a = p[0], b = p[1];
  f16x8 o = { (f16)a.x, (f16)a.y, (f16)a.z, (f16)a.w,
              (f16)b.x, (f16)b.y, (f16)b.z, (f16)b.w };
  *((f16x8*)out + i) = o;
}

__global__ void bias_cat_kernel(const float* __restrict__ bg, const float* __restrict__ bi,
                                float* __restrict__ bgi) {
  int t = threadIdx.x;  // 1024 threads
  bgi[t] = (t < 512) ? bg[t] : bi[t - 512];
}

// ---------------- m97-structure 128x128 BT GEMM (GEMM1 / GEMM3) ----------------
// MODE 0: store f16 ; MODE 2: store f32

template <int MODE>
__global__ __launch_bounds__(256, 2) void gemm_bt(
    const f16* __restrict__ A, const f16* __restrict__ Bw,
    const float* __restrict__ bias, void* __restrict__ Cout,
    int lda, int ldb, int ldc, int K) {
  __shared__ f16 lds[2][2][128][64];
  const int tid = threadIdx.x;
  const int wid = tid >> 6, lane = tid & 63;
  const int m0 = blockIdx.x * 128, n0 = blockIdx.y * 128;
  const int wr = (wid >> 1) * 64;
  const int wc = (wid & 1) * 64;
  const int NT = K >> 6;

  auto stage = [&](int buf, int kt) {
    const f16* ga = A + (size_t)m0 * lda + kt * 64;
    const f16* gb = Bw + (size_t)n0 * ldb + kt * 64;
    f16* la = &lds[buf][0][0][0];
    f16* lb = &lds[buf][1][0][0];
#pragma unroll
    for (int q = 0; q < 4; ++q) {
      int seg = (wid << 2) + q;
      int s = seg * 64 + lane;
      int row = s >> 3, col = (s & 7) << 3;
      __builtin_amdgcn_global_load_lds(AS1(ga + (size_t)row * lda + col),
                                       AS3(la + seg * 512), 16, 0, 0);
      __builtin_amdgcn_global_load_lds(AS1(gb + (size_t)row * ldb + col),
                                       AS3(lb + seg * 512), 16, 0, 0);
    }
  };

  f32x4 acc[4][4] = {};
  stage(0, 0);
  for (int kt = 0; kt < NT; ++kt) {
    __syncthreads();
    if (kt + 1 < NT) stage((kt + 1) & 1, kt + 1);
    f16(*At)[64] = lds[kt & 1][0];
    f16(*Bt)[64] = lds[kt & 1][1];
    const int r = lane & 15, cg = (lane >> 4) << 3;
#pragma unroll
    for (int kk = 0; kk < 2; ++kk) {
      f16x8 af[4], bf[4];
#pragma unroll
      for (int i = 0; i < 4; ++i)
        af[i] = *(const f16x8*)&At[wr + i * 16 + r][kk * 32 + cg];
#pragma unroll
      for (int i = 0; i < 4; ++i)
        bf[i] = *(const f16x8*)&Bt[wc + i * 16 + r][kk * 32 + cg];
#pragma unroll
      for (int mi = 0; mi < 4; ++mi)
#pragma unroll
        for (int ni = 0; ni < 4; ++ni)
          acc[mi][ni] = __builtin_amdgcn_mfma_f32_16x16x32_f16(af[mi], bf[ni], acc[mi][ni], 0, 0, 0);
    }
  }

  const int r = lane & 15, rq = (lane >> 4) * 4;
#pragma unroll
  for (int ni = 0; ni < 4; ++ni) {
    int col = n0 + wc + ni * 16 + r;
    float bv = bias[col];
#pragma unroll
    for (int mi = 0; mi < 4; ++mi) {
#pragma unroll
      for (int j = 0; j < 4; ++j) {
        int row = m0 + wr + mi * 16 + rq + j;
        float v = acc[mi][ni][j] + bv;
        if constexpr (MODE == 2)
          ((float*)Cout)[(size_t)row * ldc + col] = v;
        else
          ((f16*)Cout)[(size_t)row * ldc + col] = (f16)v;
      }
    }
  }
}

// ---------------- 8-phase 256x256 GEMM2 (h @ W1^T + b1 -> gelu -> f16) ----------------
// 8 waves (2M x 4N), BK=64 split as 4 LDS chunks [A-k0|A-k1|B-k0|B-k1] of 256x32 f16,
// double-buffered (128 KiB). Counted vmcnt(6), XOR swizzle both-sides, setprio on MFMA.

__device__ __forceinline__ float gelu_fast(float v) {
  // gelu_tanh(v) = v * sigmoid(1.5957691216*v + 0.0713548353*v^3); safe form via e^{-y}
  float u = v * v;
  float y = v * fmaf(0.0713548353f, u, 1.59576912161f);
  float e = __expf(-y);
  return v * __builtin_amdgcn_rcpf(1.0f + e);
}

__global__ __launch_bounds__(512, 2) void gemm2_8p(
    const f16* __restrict__ A, const f16* __restrict__ Bw,
    const float* __restrict__ bias, f16* __restrict__ Cout,
    int lda, int ldb, int ldc, int K) {
  __shared__ f16 ldsf[2 * 4 * 8192];  // 128 KiB
  const int tid = threadIdx.x;
  const int wid = tid >> 6, lane = tid & 63;
  const int WM = (wid >> 2) * 128, WN = (wid & 3) * 64;
  const int m0 = blockIdx.x * 256, n0 = blockIdx.y * 256;
  const int NT = K >> 6;

  // per-thread constant swizzled read offset: row_total = R + lr, slot = g ^ ((row>>1)&3)
  const int lr = lane & 15;
  const int cs = (lane >> 4) ^ ((lane >> 1) & 3);

  // staging per-thread constants (2 gload_lds per chunk per wave)
  const f16* gA[2];
  const f16* gB[2];
#pragma unroll
  for (int q = 0; q < 2; ++q) {
    int s = (wid * 2 + q) * 64 + lane;
    int row = s >> 2, c = s & 3;
    int col = (c ^ ((row >> 1) & 3)) << 3;   // pre-swizzled global source (rule #21)
    gA[q] = A + (size_t)(m0 + row) * lda + col;
    gB[q] = Bw + (size_t)(n0 + row) * ldb + col;
  }

  // chunk ids: 0=A k0, 1=A k1, 2=B k0, 3=B k1
  auto stage = [&](int buf, int which, int kt) {
    const f16* const* gp = (which < 2) ? gA : gB;
    const int kofs = kt * 64 + (which & 1) * 32;
    f16* dst = ldsf + (buf * 4 + which) * 8192 + wid * 1024;  // wave-uniform base
#pragma unroll
    for (int q = 0; q < 2; ++q)
      __builtin_amdgcn_global_load_lds(AS1(gp[q] + kofs), AS3(dst + q * 512), 16, 0, 0);
  };

  auto frag = [&](int buf, int which, int R) -> f16x8 {
    return *(const f16x8*)(ldsf + (buf * 4 + which) * 8192 + (R + lr) * 32 + (cs << 3));
  };

#define MFMA16(d, x, y) d = __builtin_amdgcn_mfma_f32_16x16x32_f16(x, y, d, 0, 0, 0)
#define FENCE() do { __builtin_amdgcn_s_barrier(); \
    asm volatile("s_waitcnt lgkmcnt(0)" ::: "memory"); \
    __builtin_amdgcn_sched_barrier(0); } while (0)

  f32x4 acc[8][4] = {};
  f16x8 a[8], b[4];

  // prologue: kt0 all 4 chunks + kt1 first 3 chunks -> wait kt0 landed (vmcnt 6)
  stage(0, 0, 0); stage(0, 2, 0); stage(0, 1, 0); stage(0, 3, 0);
  stage(1, 0, 1); stage(1, 2, 1); stage(1, 1, 1);
  asm volatile("s_waitcnt vmcnt(6)" ::: "memory");
  __builtin_amdgcn_s_barrier();

  int cur = 0;
  for (int kt = 0; kt < NT; ++kt) {
    // phase 1: read A k0 (8) + B k0 ni0,1 (2) ; stage B-k1(kt+1)
#pragma unroll
    for (int mi = 0; mi < 8; ++mi) a[mi] = frag(cur, 0, WM + mi * 16);
    b[0] = frag(cur, 2, WN);
    b[1] = frag(cur, 2, WN + 16);
    if (kt + 1 < NT) stage(cur ^ 1, 3, kt + 1);
    FENCE();
    __builtin_amdgcn_s_setprio(1);
#pragma unroll
    for (int mi = 0; mi < 8; ++mi) { MFMA16(acc[mi][0], a[mi], b[0]); MFMA16(acc[mi][1], a[mi], b[1]); }
    __builtin_amdgcn_s_setprio(0);
    __builtin_amdgcn_s_barrier();

    // phase 2: read B k0 ni2,3 (2) ; stage A-k0(kt+2)
    b[2] = frag(cur, 2, WN + 32);
    b[3] = frag(cur, 2, WN + 48);
    if (kt + 2 < NT) stage(cur, 0, kt + 2);
    FENCE();
    __builtin_amdgcn_s_setprio(1);
#pragma unroll
    for (int mi = 0; mi < 8; ++mi) { MFMA16(acc[mi][2], a[mi], b[2]); MFMA16(acc[mi][3], a[mi], b[3]); }
    __builtin_amdgcn_s_setprio(0);
    __builtin_amdgcn_s_barrier();

    // phase 3: read A k1 (8) + B k1 ni0,1 (2) ; stage B-k0(kt+2)
#pragma unroll
    for (int mi = 0; mi < 8; ++mi) a[mi] = frag(cur, 1, WM + mi * 16);
    b[0] = frag(cur, 3, WN);
    b[1] = frag(cur, 3, WN + 16);
    if (kt + 2 < NT) stage(cur, 2, kt + 2);
    FENCE();
    __builtin_amdgcn_s_setprio(1);
#pragma unroll
    for (int mi = 0; mi < 8; ++mi) { MFMA16(acc[mi][0], a[mi], b[0]); MFMA16(acc[mi][1], a[mi], b[1]); }
    __builtin_amdgcn_s_setprio(0);
    __builtin_amdgcn_s_barrier();

    // phase 4: read B k1 ni2,3 (2) ; stage A-k1(kt+2) ; counted vmcnt ; barrier
    b[2] = frag(cur, 3, WN + 32);
    b[3] = frag(cur, 3, WN + 48);
    if (kt + 2 < NT) stage(cur, 1, kt + 2);
    FENCE();
    __builtin_amdgcn_s_setprio(1);
#pragma unroll
    for (int mi = 0; mi < 8; ++mi) { MFMA16(acc[mi][2], a[mi], b[2]); MFMA16(acc[mi][3], a[mi], b[3]); }
    __builtin_amdgcn_s_setprio(0);
    if (kt + 2 < NT) asm volatile("s_waitcnt vmcnt(6)" ::: "memory");
    else             asm volatile("s_waitcnt vmcnt(0)" ::: "memory");
    __builtin_amdgcn_s_barrier();
    cur ^= 1;
  }

  // epilogue: bias + fast-gelu + f16 store
  const int rq = (lane >> 4) * 4;
#pragma unroll
  for (int ni = 0; ni < 4; ++ni) {
    int col = n0 + WN + ni * 16 + lr;
    float bv = bias[col];
#pragma unroll
    for (int mi = 0; mi < 8; ++mi) {
#pragma unroll
      for (int j = 0; j < 4; ++j) {
        int row = m0 + WM + mi * 16 + rq + j;
        float v = gelu_fast(acc[mi][ni][j] + bv);
        Cout[(size_t)row * ldc + col] = (f16)v;
      }
    }
  }
#undef MFMA16
#undef FENCE
}

// ---------------- scan (3-pass chunked) ----------------
// ab layout: row m = t*32+b, 1024 cols: [0:512)=pre_g, [512:1024)=pre_i (f16)
// h_t = g_t*h_{t-1} + (1-g_t)*i_t ; h written in-place over pre_g

#define NCH 16384
#define NCHUNK 32
#define CLEN 64

__global__ void scan_p1(const f16* __restrict__ ab, float* __restrict__ cA,
                        float* __restrict__ cH) {
  int ch = blockIdx.x * 256 + threadIdx.x;
  int c = blockIdx.y;
  const f16* pg = ab + (size_t)(c * CLEN) * 32768 + (ch >> 9) * 1024 + (ch & 511);
  const f16* pi = pg + 512;
  float A = 1.f, Hl = 0.f;
  for (int t = 0; t < CLEN; ++t) {
    float g = 1.f / (1.f + expf(-(float)pg[0]));
    float ii = tanhf((float)pi[0]);
    Hl = g * Hl + (1.f - g) * ii;
    A *= g;
    pg += 32768; pi += 32768;
  }
  cA[c * NCH + ch] = A;
  cH[c * NCH + ch] = Hl;
}

__global__ void scan_p2(const float* __restrict__ cA, const float* __restrict__ cH,
                        float* __restrict__ st) {
  int ch = blockIdx.x * 256 + threadIdx.x;
  float h0 = 0.f;
  for (int c = 0; c < NCHUNK; ++c) {
    st[c * NCH + ch] = h0;
    h0 = cA[c * NCH + ch] * h0 + cH[c * NCH + ch];
  }
}

__global__ void scan_p3(f16* __restrict__ ab, const float* __restrict__ st) {
  int ch = blockIdx.x * 256 + threadIdx.x;
  int c = blockIdx.y;
  f16* pg = ab + (size_t)(c * CLEN) * 32768 + (ch >> 9) * 1024 + (ch & 511);
  const f16* pi = pg + 512;
  float hv = st[c * NCH + ch];
  for (int t = 0; t < CLEN; ++t) {
    float g = 1.f / (1.f + expf(-(float)pg[0]));
    float ii = tanhf((float)pi[0]);
    hv = g * hv + (1.f - g) * ii;
    pg[0] = (f16)hv;
    pg += 32768; pi += 32768;
  }
}

// ---------------- launch ----------------

extern "C" void kernel_launch(void* const* d_in, const int* in_sizes, int n_in,
                              void* d_out, int out_size, void* d_ws, size_t ws_size,
                              hipStream_t stream) {
  const float* x  = (const float*)d_in[0];
  const float* Wg = (const float*)d_in[1];
  const float* bg = (const float*)d_in[2];
  const float* Wi = (const float*)d_in[3];
  const float* bi = (const float*)d_in[4];
  const float* W1 = (const float*)d_in[5];
  const float* b1 = (const float*)d_in[6];
  const float* W2 = (const float*)d_in[7];
  const float* b2 = (const float*)d_in[8];
  float* out = (float*)d_out;

  char* ws = (char*)d_ws;
  f16*   wgi16 = (f16*)(ws + 0);            // 1024x256 f16
  f16*   w116  = (f16*)(ws + 524288);       // 2048x512 f16
  f16*   w216  = (f16*)(ws + 2621440);      // 256x2048 f16
  float* bgi   = (float*)(ws + 3670016);    // 1024 f32
  f16*   x16   = (f16*)(ws + 4194304);      // 65536x256 f16
  f16*   ab16  = (f16*)(ws + 37748736);     // 65536x1024 f16
  float* cA    = (float*)(ws + 171966464);  // 32x16384 f32
  float* cH    = (float*)(ws + 174063616);
  float* st    = (float*)(ws + 176160768);
  f16*   z16   = (f16*)(ws + 178257920);    // 16384x2048 f16
  if (ws_size < 245366784) return;

  // prep
  cvt_kernel<<<64, 256, 0, stream>>>(Wg, wgi16, 16384);
  cvt_kernel<<<64, 256, 0, stream>>>(Wi, wgi16 + 131072, 16384);
  cvt_kernel<<<512, 256, 0, stream>>>(W1, w116, 131072);
  cvt_kernel<<<256, 256, 0, stream>>>(W2, w216, 65536);
  bias_cat_kernel<<<1, 1024, 0, stream>>>(bg, bi, bgi);
  cvt_kernel<<<8192, 256, 0, stream>>>(x, x16, 2097152);

  // GEMM1: pre = x @ [Wg;Wi]^T + [bg;bi]  -> ab16 (f16, ldc=1024)
  gemm_bt<0><<<dim3(512, 8), 256, 0, stream>>>(x16, wgi16, bgi, ab16,
                                               IN_DIM, IN_DIM, 1024, IN_DIM);

  // scan
  scan_p1<<<dim3(64, NCHUNK), 256, 0, stream>>>(ab16, cA, cH);
  scan_p2<<<64, 256, 0, stream>>>(cA, cH, st);
  scan_p3<<<dim3(64, NCHUNK), 256, 0, stream>>>(ab16, st);

  // 4 T-slabs: GEMM2 (8-phase, gelu) -> z16 ; GEMM3 -> out
  for (int s = 0; s < 4; ++s) {
    const f16* hs = ab16 + (size_t)s * 16384 * 1024;
    gemm2_8p<<<dim3(64, 8), 512, 0, stream>>>(hs, w116, b1, z16,
                                              1024, H_DIM, F_DIM, H_DIM);
    gemm_bt<2><<<dim3(128, 2), 256, 0, stream>>>(z16, w216, b2,
                                                 out + (size_t)s * 16384 * 256,
                                                 F_DIM, F_DIM, OUT_DIM, F_DIM);
  }
}

// Round 3
// 534.597 us; speedup vs baseline: 1.1620x; 1.0991x over previous
//
#include <hip/hip_runtime.h>
#include <hip/hip_fp16.h>
#include <math.h>

// GILR model: T=2048 B=32 IN=256 H=512 F=2048 OUT=256
//   prep: f32->f16 convert of x, Wg|Wi (stacked), W1, W2; concat bg|bi
//   GEMM1: pre = x@[Wg;Wi]^T + [bg;bi]  (f16, 65536x1024)  [m97 structure + XCD swizzle]
//   scan : 3-pass chunked associative scan; h written in-place over pre_g
//   4 T-slabs: GEMM2 (256x128 tile, BK=32, 3-buf, 2 blocks/CU, fast-gelu, f16)
//              GEMM3 (m97 structure, f32 out)

#define T_DIM 2048
#define B_DIM 32
#define IN_DIM 256
#define H_DIM 512
#define F_DIM 2048
#define OUT_DIM 256

typedef _Float16 f16;
typedef _Float16 f16x8 __attribute__((ext_vector_type(8)));
typedef float f32x4 __attribute__((ext_vector_type(4)));

#define AS3(p) ((__attribute__((address_space(3))) void*)(p))
#define AS1(p) ((const __attribute__((address_space(1))) void*)(p))
#define MFMA16(d, x, y) d = __builtin_amdgcn_mfma_f32_16x16x32_f16(x, y, d, 0, 0, 0)

// ---------------- conversion kernels ----------------

__global__ void cvt_kernel(const float* __restrict__ in, f16* __restrict__ out, int n8) {
  int i = blockIdx.x * blockDim.x + threadIdx.x;
  if (i >= n8) return;
  const float4* p = (const float4*)in + (size_t)i * 2;
  float4 a = p[0], b = p[1];
  f16x8 o = { (f16)a.x, (f16)a.y, (f16)a.z, (f16)a.w,
              (f16)b.x, (f16)b.y, (f16)b.z, (f16)b.w };
  *((f16x8*)out + i) = o;
}

__global__ void bias_cat_kernel(const float* __restrict__ bg, const float* __restrict__ bi,
                                float* __restrict__ bgi) {
  int t = threadIdx.x;  // 1024 threads
  bgi[t] = (t < 512) ? bg[t] : bi[t - 512];
}

// ---------------- m97-structure 128x128 BT GEMM (GEMM1 / GEMM3) ----------------
// 1-D grid with XCD-chunked swizzle: xcd = bid&7 owns m-tiles [xcd*MPX, xcd*MPX+MPX),
// n-tile varies fastest (1<<LN n-tiles). MODE 0: store f16 ; MODE 2: store f32.

template <int MODE, int LN, int MPX>
__global__ __launch_bounds__(256, 2) void gemm_bt(
    const f16* __restrict__ A, const f16* __restrict__ Bw,
    const float* __restrict__ bias, void* __restrict__ Cout,
    int lda, int ldb, int ldc, int K) {
  __shared__ f16 lds[2][2][128][64];
  const int tid = threadIdx.x;
  const int wid = tid >> 6, lane = tid & 63;
  const int bid = blockIdx.x;
  const int xcd = bid & 7, loc = bid >> 3;
  const int m0 = (xcd * MPX + (loc >> LN)) * 128;
  const int n0 = (loc & ((1 << LN) - 1)) * 128;
  const int wr = (wid >> 1) * 64;
  const int wc = (wid & 1) * 64;
  const int NT = K >> 6;

  auto stage = [&](int buf, int kt) {
    const f16* ga = A + (size_t)m0 * lda + kt * 64;
    const f16* gb = Bw + (size_t)n0 * ldb + kt * 64;
    f16* la = &lds[buf][0][0][0];
    f16* lb = &lds[buf][1][0][0];
#pragma unroll
    for (int q = 0; q < 4; ++q) {
      int seg = (wid << 2) + q;
      int s = seg * 64 + lane;
      int row = s >> 3, col = (s & 7) << 3;
      __builtin_amdgcn_global_load_lds(AS1(ga + (size_t)row * lda + col),
                                       AS3(la + seg * 512), 16, 0, 0);
      __builtin_amdgcn_global_load_lds(AS1(gb + (size_t)row * ldb + col),
                                       AS3(lb + seg * 512), 16, 0, 0);
    }
  };

  f32x4 acc[4][4] = {};
  stage(0, 0);
  for (int kt = 0; kt < NT; ++kt) {
    __syncthreads();
    if (kt + 1 < NT) stage((kt + 1) & 1, kt + 1);
    f16(*At)[64] = lds[kt & 1][0];
    f16(*Bt)[64] = lds[kt & 1][1];
    const int r = lane & 15, cg = (lane >> 4) << 3;
#pragma unroll
    for (int kk = 0; kk < 2; ++kk) {
      f16x8 af[4], bf[4];
#pragma unroll
      for (int i = 0; i < 4; ++i)
        af[i] = *(const f16x8*)&At[wr + i * 16 + r][kk * 32 + cg];
#pragma unroll
      for (int i = 0; i < 4; ++i)
        bf[i] = *(const f16x8*)&Bt[wc + i * 16 + r][kk * 32 + cg];
#pragma unroll
      for (int mi = 0; mi < 4; ++mi)
#pragma unroll
        for (int ni = 0; ni < 4; ++ni)
          acc[mi][ni] = __builtin_amdgcn_mfma_f32_16x16x32_f16(af[mi], bf[ni], acc[mi][ni], 0, 0, 0);
    }
  }

  const int r = lane & 15, rq = (lane >> 4) * 4;
#pragma unroll
  for (int ni = 0; ni < 4; ++ni) {
    int col = n0 + wc + ni * 16 + r;
    float bv = bias[col];
#pragma unroll
    for (int mi = 0; mi < 4; ++mi) {
#pragma unroll
      for (int j = 0; j < 4; ++j) {
        int row = m0 + wr + mi * 16 + rq + j;
        float v = acc[mi][ni][j] + bv;
        if constexpr (MODE == 2)
          ((float*)Cout)[(size_t)row * ldc + col] = v;
        else
          ((f16*)Cout)[(size_t)row * ldc + col] = (f16)v;
      }
    }
  }
}

// ---------------- GEMM2: 256x128 tile, 4 waves, BK=32, 3-buf, 2 blocks/CU ----------------
// z = gelu(h @ W1^T + b1), h: [16384 x 512] (lda=1024), W1: [2048 x 512], z f16 ldc=2048.
// LDS per buf: A 256x32 (16KB) + B 128x32 (8KB) = 24KB; 3 bufs = 72KB -> 2 blocks/CU.
// Both-sides XOR swizzle on 16B chunks: g = c ^ ((row + (row>>2)) & 3).
// Prefetch 2 K-tiles ahead; counted vmcnt(6). Vectorized LDS-transpose epilogue.

__device__ __forceinline__ float gelu_fast(float v) {
  float u = v * v;
  float y = v * fmaf(0.0713548353f, u, 1.59576912161f);
  float e = __expf(-y);
  return v * __builtin_amdgcn_rcpf(1.0f + e);
}

__global__ __launch_bounds__(256, 2) void gemm2_f(
    const f16* __restrict__ A, const f16* __restrict__ Bw,
    const float* __restrict__ bias, f16* __restrict__ Cout) {
  constexpr int LDA = 1024, LDB = 512, LDC = 2048, K = 512, NT = K / 32;
  __shared__ f16 lds[3][384 * 32];   // 72 KiB
  const int tid = threadIdx.x, wid = tid >> 6, lane = tid & 63;
  const int lr = lane & 15;
  // grid 1024: xcd = bid&7 -> m-chunk; n fastest (16 n-tiles)
  const int bid = blockIdx.x;
  const int m0 = ((bid & 7) * 8 + (bid >> 7)) * 256;
  const int n0 = ((bid >> 3) & 15) * 128;
  const int wr = (wid >> 1) * 128, wc = (wid & 1) * 64;

  // staging source pointers (global side pre-swizzled, rule #21)
  const f16* srcA[4];
  const f16* srcB[2];
#pragma unroll
  for (int q = 0; q < 4; ++q) {
    int s = wid * 256 + q * 64 + lane;
    int row = s >> 2, g = (s & 3) ^ ((row + (row >> 2)) & 3);
    srcA[q] = A + (size_t)(m0 + row) * LDA + g * 8;
  }
#pragma unroll
  for (int q = 0; q < 2; ++q) {
    int s = wid * 128 + q * 64 + lane;
    int row = s >> 2, g = (s & 3) ^ ((row + (row >> 2)) & 3);
    srcB[q] = Bw + (size_t)(n0 + row) * LDB + g * 8;
  }

  auto stageA = [&](int buf, int kt) {
    f16* d = lds[buf] + wid * 2048;
#pragma unroll
    for (int q = 0; q < 4; ++q)
      __builtin_amdgcn_global_load_lds(AS1(srcA[q] + kt * 32), AS3(d + q * 512), 16, 0, 0);
  };
  auto stageB = [&](int buf, int kt) {
    f16* d = lds[buf] + 8192 + wid * 1024;
#pragma unroll
    for (int q = 0; q < 2; ++q)
      __builtin_amdgcn_global_load_lds(AS1(srcB[q] + kt * 32), AS3(d + q * 512), 16, 0, 0);
  };

  // read-side swizzle folds to a per-thread constant (f(row) == f(lr) for row=16k+lr)
  const int qsf = (((lane >> 4) ^ ((lr + (lr >> 2)) & 3)) << 3);
  auto fragA = [&](int buf, int mi) -> f16x8 {
    return *(const f16x8*)(lds[buf] + (wr + mi * 16 + lr) * 32 + qsf);
  };
  auto fragB = [&](int buf, int ni) -> f16x8 {
    return *(const f16x8*)(lds[buf] + 8192 + (wc + ni * 16 + lr) * 32 + qsf);
  };

  f32x4 acc[8][4] = {};
  stageA(0, 0); stageB(0, 0);
  stageA(1, 1); stageB(1, 1);
  asm volatile("s_waitcnt vmcnt(6)" ::: "memory");   // kt0 landed (own wave)
  __builtin_amdgcn_s_barrier();

#pragma unroll
  for (int kt = 0; kt < NT; ++kt) {
    const int cur = kt % 3, nx2 = (kt + 2) % 3;
    f16x8 a[8], b[4];
    // phase 1: A frags + B0,B1 ; stage A(kt+2)
#pragma unroll
    for (int mi = 0; mi < 8; ++mi) a[mi] = fragA(cur, mi);
    b[0] = fragB(cur, 0);
    b[1] = fragB(cur, 1);
    if (kt + 2 < NT) stageA(nx2, kt + 2);
    __builtin_amdgcn_s_barrier();
    asm volatile("s_waitcnt lgkmcnt(0)" ::: "memory");
    __builtin_amdgcn_sched_barrier(0);
    __builtin_amdgcn_s_setprio(1);
#pragma unroll
    for (int mi = 0; mi < 8; ++mi) { MFMA16(acc[mi][0], a[mi], b[0]); MFMA16(acc[mi][1], a[mi], b[1]); }
    __builtin_amdgcn_s_setprio(0);
    __builtin_amdgcn_s_barrier();
    // phase 2: B2,B3 ; stage B(kt+2) ; counted vmcnt
    b[2] = fragB(cur, 2);
    b[3] = fragB(cur, 3);
    if (kt + 2 < NT) stageB(nx2, kt + 2);
    __builtin_amdgcn_s_barrier();
    asm volatile("s_waitcnt lgkmcnt(0)" ::: "memory");
    __builtin_amdgcn_sched_barrier(0);
    __builtin_amdgcn_s_setprio(1);
#pragma unroll
    for (int mi = 0; mi < 8; ++mi) { MFMA16(acc[mi][2], a[mi], b[2]); MFMA16(acc[mi][3], a[mi], b[3]); }
    __builtin_amdgcn_s_setprio(0);
    if (kt + 2 < NT) asm volatile("s_waitcnt vmcnt(6)" ::: "memory");
    else             asm volatile("s_waitcnt vmcnt(0)" ::: "memory");
    __builtin_amdgcn_s_barrier();
  }

  // ---- epilogue: per-wave 16KB LDS transpose -> coalesced f16x8 stores ----
  __syncthreads();
  f16* ep = &lds[0][0] + wid * 8192;   // 128 rows x 64 f16, row-XOR chunk swizzle
  const int rq = (lane >> 4) * 4;
#pragma unroll
  for (int mi = 0; mi < 8; ++mi) {
#pragma unroll
    for (int ni = 0; ni < 4; ++ni) {
      int c = ni * 2 + (lr >> 3);
      float bv = bias[n0 + wc + ni * 16 + lr];
#pragma unroll
      for (int j = 0; j < 4; ++j) {
        int row = mi * 16 + rq + j;
        float v = gelu_fast(acc[mi][ni][j] + bv);
        ep[row * 64 + ((c ^ (row & 7)) << 3) + (lr & 7)] = (f16)v;
      }
    }
  }
  asm volatile("s_waitcnt lgkmcnt(0)" ::: "memory");
  __builtin_amdgcn_sched_barrier(0);
#pragma unroll
  for (int t = 0; t < 16; ++t) {
    int idx = t * 64 + lane;
    int row = idx >> 3, c = idx & 7;
    f16x8 v = *(const f16x8*)(ep + row * 64 + ((c ^ (row & 7)) << 3));
    *(f16x8*)(Cout + (size_t)(m0 + wr + row) * LDC + (n0 + wc) + c * 8) = v;
  }
}

// ---------------- scan (3-pass chunked) ----------------
// ab layout: row m = t*32+b, 1024 cols: [0:512)=pre_g, [512:1024)=pre_i (f16)
// h_t = g_t*h_{t-1} + (1-g_t)*i_t ; h written in-place over pre_g

#define NCH 16384
#define NCHUNK 32
#define CLEN 64

__global__ void scan_p1(const f16* __restrict__ ab, float* __restrict__ cA,
                        float* __restrict__ cH) {
  int ch = blockIdx.x * 256 + threadIdx.x;
  int c = blockIdx.y;
  const f16* pg = ab + (size_t)(c * CLEN) * 32768 + (ch >> 9) * 1024 + (ch & 511);
  const f16* pi = pg + 512;
  float A = 1.f, Hl = 0.f;
  for (int t = 0; t < CLEN; ++t) {
    float g = 1.f / (1.f + expf(-(float)pg[0]));
    float ii = tanhf((float)pi[0]);
    Hl = g * Hl + (1.f - g) * ii;
    A *= g;
    pg += 32768; pi += 32768;
  }
  cA[c * NCH + ch] = A;
  cH[c * NCH + ch] = Hl;
}

__global__ void scan_p2(const float* __restrict__ cA, const float* __restrict__ cH,
                        float* __restrict__ st) {
  int ch = blockIdx.x * 256 + threadIdx.x;
  float h0 = 0.f;
  for (int c = 0; c < NCHUNK; ++c) {
    st[c * NCH + ch] = h0;
    h0 = cA[c * NCH + ch] * h0 + cH[c * NCH + ch];
  }
}

__global__ void scan_p3(f16* __restrict__ ab, const float* __restrict__ st) {
  int ch = blockIdx.x * 256 + threadIdx.x;
  int c = blockIdx.y;
  f16* pg = ab + (size_t)(c * CLEN) * 32768 + (ch >> 9) * 1024 + (ch & 511);
  const f16* pi = pg + 512;
  float hv = st[c * NCH + ch];
  for (int t = 0; t < CLEN; ++t) {
    float g = 1.f / (1.f + expf(-(float)pg[0]));
    float ii = tanhf((float)pi[0]);
    hv = g * hv + (1.f - g) * ii;
    pg[0] = (f16)hv;
    pg += 32768; pi += 32768;
  }
}

// ---------------- launch ----------------

extern "C" void kernel_launch(void* const* d_in, const int* in_sizes, int n_in,
                              void* d_out, int out_size, void* d_ws, size_t ws_size,
                              hipStream_t stream) {
  const float* x  = (const float*)d_in[0];
  const float* Wg = (const float*)d_in[1];
  const float* bg = (const float*)d_in[2];
  const float* Wi = (const float*)d_in[3];
  const float* bi = (const float*)d_in[4];
  const float* W1 = (const float*)d_in[5];
  const float* b1 = (const float*)d_in[6];
  const float* W2 = (const float*)d_in[7];
  const float* b2 = (const float*)d_in[8];
  float* out = (float*)d_out;

  char* ws = (char*)d_ws;
  f16*   wgi16 = (f16*)(ws + 0);            // 1024x256 f16
  f16*   w116  = (f16*)(ws + 524288);       // 2048x512 f16
  f16*   w216  = (f16*)(ws + 2621440);      // 256x2048 f16
  float* bgi   = (float*)(ws + 3670016);    // 1024 f32
  f16*   x16   = (f16*)(ws + 4194304);      // 65536x256 f16
  f16*   ab16  = (f16*)(ws + 37748736);     // 65536x1024 f16
  float* cA    = (float*)(ws + 171966464);  // 32x16384 f32
  float* cH    = (float*)(ws + 174063616);
  float* st    = (float*)(ws + 176160768);
  f16*   z16   = (f16*)(ws + 178257920);    // 16384x2048 f16
  if (ws_size < 245366784) return;

  // prep
  cvt_kernel<<<64, 256, 0, stream>>>(Wg, wgi16, 16384);
  cvt_kernel<<<64, 256, 0, stream>>>(Wi, wgi16 + 131072, 16384);
  cvt_kernel<<<512, 256, 0, stream>>>(W1, w116, 131072);
  cvt_kernel<<<256, 256, 0, stream>>>(W2, w216, 65536);
  bias_cat_kernel<<<1, 1024, 0, stream>>>(bg, bi, bgi);
  cvt_kernel<<<8192, 256, 0, stream>>>(x, x16, 2097152);

  // GEMM1: pre = x @ [Wg;Wi]^T + [bg;bi]  -> ab16 (f16, ldc=1024); 512 m-tiles x 8 n-tiles
  gemm_bt<0, 3, 64><<<4096, 256, 0, stream>>>(x16, wgi16, bgi, ab16,
                                              IN_DIM, IN_DIM, 1024, IN_DIM);

  // scan
  scan_p1<<<dim3(64, NCHUNK), 256, 0, stream>>>(ab16, cA, cH);
  scan_p2<<<64, 256, 0, stream>>>(cA, cH, st);
  scan_p3<<<dim3(64, NCHUNK), 256, 0, stream>>>(ab16, st);

  // 4 T-slabs: GEMM2 -> z16 ; GEMM3 -> out
  for (int s = 0; s < 4; ++s) {
    const f16* hs = ab16 + (size_t)s * 16384 * 1024;
    gemm2_f<<<1024, 256, 0, stream>>>(hs, w116, b1, z16);
    // GEMM3: 128 m-tiles x 2 n-tiles
    gemm_bt<2, 1, 16><<<256, 256, 0, stream>>>(z16, w216, b2,
                                               out + (size_t)s * 16384 * 256,
                                               F_DIM, F_DIM, OUT_DIM, F_DIM);
  }
}